// Round 6
// baseline (72.829 us; speedup 1.0000x reference)
//
#include <hip/hip_runtime.h>
#include <hip/hip_bf16.h>

#define B_   2
#define L_   2048
#define C_   256
#define H_   8
#define DK_  32
#define HD_  256
#define RSQRT_DK 0.17677669529663687f  // 1/sqrt(32)

typedef __attribute__((ext_vector_type(8))) short bf16x8;
typedef __attribute__((ext_vector_type(4))) float f32x4;

__device__ __forceinline__ unsigned short f2bf(float x) {
    unsigned int u = __float_as_uint(x);
    u += 0x7fffu + ((u >> 16) & 1u);
    return (unsigned short)(u >> 16);
}
__device__ __forceinline__ float bf2f(unsigned short h) {
    return __uint_as_float((unsigned int)h << 16);
}

// ---------------------------------------------------------------------------
// Split-bf16 transposed weight slice in LDS: plane[64][256] shorts.
// Row pitch = 128 dwords (== 0 mod 32 banks -> uniform row bank base).
// 16B chunk index swizzled: chunk' = chunk ^ (n & 7)  (st_16x32-style).
// Both ds_write_b128 staging and ds_read_b128 frag reads sit at the b128
// bank floor (uniform 8-deep).
// ---------------------------------------------------------------------------
#define WT_IDX(n, k) (((n) << 8) + (((((k) >> 3) ^ ((n) & 7))) << 3) + ((k) & 7))

// Stage W cols [n0, n0+63], k 0..255 into LDS planes as split-bf16 [n][k].
// 256 threads: wave w handles k-rows [w*64, w*64+63]; lane n = tid&63.
// Global loads: 64 consecutive lanes read 64 consecutive floats (coalesced).
__device__ __forceinline__ void stage_wT(
    const float* __restrict__ W, int n0, int tid,
    short* __restrict__ WTh, short* __restrict__ WTl)
{
    const int n  = tid & 63;
    const int kc = tid >> 6;           // 0..3
    #pragma unroll
    for (int c8 = 0; c8 < 8; ++c8) {
        const int k0 = kc * 64 + c8 * 8;
        bf16x8 hv, lv;
        #pragma unroll
        for (int e = 0; e < 8; ++e) {
            const float x = W[(size_t)(k0 + e) * HD_ + n0 + n];
            const unsigned short h = f2bf(x);
            hv[e] = (short)h;
            lv[e] = (short)f2bf(x - bf2f(h));
        }
        const int o = (n << 8) + ((((k0 >> 3) ^ (n & 7))) << 3);
        *reinterpret_cast<bf16x8*>(&WTh[o]) = hv;
        *reinterpret_cast<bf16x8*>(&WTl[o]) = lv;
    }
}

// ---------------------------------------------------------------------------
// K1: QKV projection, split-bf16 MFMA, fused weight transpose (LDS,
// conflict-free), deterministic per-block V column-sum partials.
// Grid (32, 12 = proj*4 + nt), 256 thr = 4 waves; block tile 128x64,
// wave tile 32x64.
// ---------------------------------------------------------------------------
__global__ __launch_bounds__(256) void gemm_qkv_fused(
    const float* __restrict__ qx, const float* __restrict__ kx, const float* __restrict__ vx,
    const float* __restrict__ WQ, const float* __restrict__ bQ,
    const float* __restrict__ WK, const float* __restrict__ bK,
    const float* __restrict__ WV, const float* __restrict__ bV,
    float* __restrict__ q, float* __restrict__ k, float* __restrict__ v,
    float* __restrict__ part)
{
    const int bx = blockIdx.x;          // 0..31
    const int yy = blockIdx.y;          // 0..11
    const int proj = yy >> 2, nt = yy & 3;
    const float* A    = proj == 0 ? qx : (proj == 1 ? kx : vx);
    const float* W    = proj == 0 ? WQ : (proj == 1 ? WK : WV);
    const float* bias = proj == 0 ? bQ : (proj == 1 ? bK : bV);
    float* out        = proj == 0 ? q  : (proj == 1 ? k  : v);
    const int n0 = nt * 64;

    __shared__ short WTh[64 * 256];
    __shared__ short WTl[64 * 256];
    __shared__ float red[4][4][16];

    const int tid = threadIdx.x;
    stage_wT(W, n0, tid, WTh, WTl);
    __syncthreads();

    const int w  = tid >> 6;            // wave 0..3
    const int l  = tid & 63;
    const int lm = l & 15, lk8 = (l >> 4) * 8, cr = (l >> 4) * 4;
    const int R  = bx * 128 + w * 32;

    f32x4 acc[2][4];
    #pragma unroll
    for (int mf = 0; mf < 2; ++mf)
        #pragma unroll
        for (int nf = 0; nf < 4; ++nf)
            acc[mf][nf] = (f32x4){0.f, 0.f, 0.f, 0.f};

    float4 Ab[2][4];
    #define LOAD_A(buf, ks)                                                          \
    {                                                                                \
        const float* p0 = &A[(size_t)(R + lm) * C_ + (ks) * 32 + lk8];               \
        const float* p1 = &A[(size_t)(R + 16 + lm) * C_ + (ks) * 32 + lk8];          \
        Ab[buf][0] = *reinterpret_cast<const float4*>(p0);                           \
        Ab[buf][1] = *reinterpret_cast<const float4*>(p0 + 4);                       \
        Ab[buf][2] = *reinterpret_cast<const float4*>(p1);                           \
        Ab[buf][3] = *reinterpret_cast<const float4*>(p1 + 4);                       \
    }
    LOAD_A(0, 0)
    LOAD_A(1, 1)

    #pragma unroll
    for (int ks = 0; ks < 8; ++ks) {
        const int cur = ks & 1;
        bf16x8 ah[2], al[2];
        #pragma unroll
        for (int mf = 0; mf < 2; ++mf) {
            float4 v0 = Ab[cur][mf * 2], v1 = Ab[cur][mf * 2 + 1];
            float xs[8] = {v0.x, v0.y, v0.z, v0.w, v1.x, v1.y, v1.z, v1.w};
            #pragma unroll
            for (int e = 0; e < 8; ++e) {
                const unsigned short h = f2bf(xs[e]);
                ah[mf][e] = (short)h;
                al[mf][e] = (short)f2bf(xs[e] - bf2f(h));
            }
        }
        if (ks < 6) LOAD_A(cur, ks + 2)
        bf16x8 Bh[4], Bl[4];
        #pragma unroll
        for (int nf = 0; nf < 4; ++nf) {
            const int o = WT_IDX(nf * 16 + lm, ks * 32 + lk8);
            Bh[nf] = *reinterpret_cast<const bf16x8*>(&WTh[o]);
            Bl[nf] = *reinterpret_cast<const bf16x8*>(&WTl[o]);
        }
        #pragma unroll
        for (int mf = 0; mf < 2; ++mf)
            #pragma unroll
            for (int nf = 0; nf < 4; ++nf) {
                acc[mf][nf] = __builtin_amdgcn_mfma_f32_16x16x32_bf16(ah[mf], Bh[nf], acc[mf][nf], 0, 0, 0);
                acc[mf][nf] = __builtin_amdgcn_mfma_f32_16x16x32_bf16(ah[mf], Bl[nf], acc[mf][nf], 0, 0, 0);
                acc[mf][nf] = __builtin_amdgcn_mfma_f32_16x16x32_bf16(al[mf], Bh[nf], acc[mf][nf], 0, 0, 0);
            }
    }
    #undef LOAD_A

    // epilogue: bias + scatter to (B,H,L,DK)
    #pragma unroll
    for (int mf = 0; mf < 2; ++mf)
        #pragma unroll
        for (int nf = 0; nf < 4; ++nf) {
            const int col = n0 + nf * 16 + lm;
            const int h = col >> 5, d = col & 31;
            const float bb = bias[col];
            #pragma unroll
            for (int r = 0; r < 4; ++r) {
                const int m = R + mf * 16 + cr + r;
                const int b = m >> 11, lrow = m & (L_ - 1);
                out[((size_t)(b * H_ + h) * L_ + lrow) * DK_ + d] = acc[mf][nf][r] + bb;
            }
        }

    // V column-sum partials (deterministic, per block = 128 rows x 64 cols)
    if (proj == 2) {
        float sl[4];
        #pragma unroll
        for (int nf = 0; nf < 4; ++nf) {
            float s = 0.f;
            #pragma unroll
            for (int mf = 0; mf < 2; ++mf)
                #pragma unroll
                for (int r = 0; r < 4; ++r) s += acc[mf][nf][r];
            s += __shfl_xor(s, 16);
            s += __shfl_xor(s, 32);
            sl[nf] = s;
        }
        if (l < 16) {
            #pragma unroll
            for (int nf = 0; nf < 4; ++nf) red[w][nf][l] = sl[nf];
        }
        __syncthreads();
        if (tid < 64) {
            const int nf = tid >> 4, lmm = tid & 15;
            float tot = red[0][nf][lmm] + red[1][nf][lmm] + red[2][nf][lmm] + red[3][nf][lmm];
            const int col = n0 + nf * 16 + lmm;
            tot += 128.f * bias[col];
            const int h = col >> 5, d = col & 31;
            const int bh = (bx >> 4) * H_ + h;       // block spans one b
            part[((size_t)bh * 32 + d) * 16 + (bx & 15)] = tot;
        }
    }
}

// ---------------------------------------------------------------------------
// K2: attention.
//  Blocks 0..31   : global rows 0 / L-1, one block per (bh,row), dense
//                   2048-col softmax in LDS.
//  Blocks 32..287 : interior rows, ONE ROW PER LANE (bh = blk>>4, 128-row
//                   chunk = blk&15), K/V/Q staged in LDS, XOR-quad swizzle.
// 128 threads (2 waves) per block.
// ---------------------------------------------------------------------------
#define NSLOT 392            // 132 K + 132 V + 128 Q
#define KOFF  0
#define VOFF  132
#define QOFF  264

__global__ __launch_bounds__(128) void attn_main(
    const float* __restrict__ q, const float* __restrict__ k,
    const float* __restrict__ v, const float* __restrict__ part,
    unsigned short* __restrict__ zh, unsigned short* __restrict__ zl)
{
    __shared__ float Sf[NSLOT * 32 + 32];
    float* vs_sh = &Sf[NSLOT * 32];

    // logical (slot, quad, elem) -> phys dword: slot*32 + ((quad ^ (slot&7))<<2) + elem
    #define LDS_F4(slot, u2) (*reinterpret_cast<const float4*>(&Sf[((slot) << 5) + (((u2) ^ ((slot) & 7)) << 2)]))

    const int blk = blockIdx.x;
    const int t = threadIdx.x;

    if (blk >= 32) {
        // ----------------- interior rows, per-lane -----------------
        const int blk2 = blk - 32;                  // 0..255
        const int bh = blk2 >> 4, c = blk2 & 15;
        const int base = c * 128;                   // slot s (<130) = row base+s
        const float* qb = q + (size_t)bh * L_ * DK_;
        const float* kb = k + (size_t)bh * L_ * DK_;
        const float* vb = v + (size_t)bh * L_ * DK_;

        // stage K(132 slots) V(132) Q(128) = 3136 float4 units
        for (int u = t; u < NSLOT * 8; u += 128) {
            const int slot = u >> 3, quad = u & 7;
            int row; const float* src;
            if (slot < VOFF) {
                const int s = slot;
                row = (s < 130) ? min(base + s, L_ - 1) : ((s == 130) ? 0 : L_ - 1);
                src = kb;
            } else if (slot < QOFF) {
                const int s = slot - VOFF;
                row = (s < 130) ? min(base + s, L_ - 1) : ((s == 130) ? 0 : L_ - 1);
                src = vb;
            } else {
                row = min(base + 1 + (slot - QOFF), L_ - 1);
                src = qb;
            }
            float4 w4 = *reinterpret_cast<const float4*>(&src[(size_t)row * DK_ + quad * 4]);
            float* dst = &Sf[(slot << 5) + ((quad ^ (slot & 7)) << 2)];
            dst[0] = w4.x; dst[1] = w4.y; dst[2] = w4.z; dst[3] = w4.w;
        }
        if (t < 32) {
            const float4* pp = reinterpret_cast<const float4*>(&part[((size_t)bh * 32 + t) * 16]);
            float4 pa = pp[0], pb = pp[1], pc = pp[2], pd = pp[3];
            vs_sh[t] = pa.x + pa.y + pa.z + pa.w + pb.x + pb.y + pb.z + pb.w
                     + pc.x + pc.y + pc.z + pc.w + pd.x + pd.y + pd.z + pd.w;
        }
        __syncthreads();

        const int i = base + 1 + t;
        if (i <= L_ - 2) {
            float qr[32];
            {
                const int qs = QOFF + t;
                #pragma unroll
                for (int u2 = 0; u2 < 8; ++u2) {
                    float4 x = LDS_F4(qs, u2);
                    qr[u2 * 4 + 0] = x.x; qr[u2 * 4 + 1] = x.y;
                    qr[u2 * 4 + 2] = x.z; qr[u2 * 4 + 3] = x.w;
                }
            }
            const int ks_[5] = {130, t, t + 1, t + 2, 131};   // cols 0, i-1, i, i+1, L-1
            float sv[5];
            #pragma unroll
            for (int jj = 0; jj < 5; ++jj) {
                const int s = ks_[jj];
                float p = 0.f;
                #pragma unroll
                for (int u2 = 0; u2 < 8; ++u2) {
                    float4 kv = LDS_F4(s, u2);
                    p += qr[u2 * 4 + 0] * kv.x + qr[u2 * 4 + 1] * kv.y
                       + qr[u2 * 4 + 2] * kv.z + qr[u2 * 4 + 3] * kv.w;
                }
                sv[jj] = p * RSQRT_DK;
            }
            const bool v1 = (i != 1), v3 = (i != L_ - 2);
            float m = fmaxf(0.f, sv[0]);                 // zero fillers join the max
            m = fmaxf(m, sv[2]); m = fmaxf(m, sv[4]);
            if (v1) m = fmaxf(m, sv[1]);
            if (v3) m = fmaxf(m, sv[3]);
            float e[5];
            e[0] = __expf(sv[0] - m);
            e[1] = v1 ? __expf(sv[1] - m) : 0.f;
            e[2] = __expf(sv[2] - m);
            e[3] = v3 ? __expf(sv[3] - m) : 0.f;
            e[4] = __expf(sv[4] - m);
            const int ns = 3 + (int)v1 + (int)v3;
            const float e0 = __expf(-m);
            const float Z = e[0] + e[1] + e[2] + e[3] + e[4] + (float)(L_ - ns) * e0;
            const float rZ = 1.f / Z;
            const float f1 = v1 ? 1.f : 0.f, f3 = v3 ? 1.f : 0.f;

            bf16x8 zh8[4], zl8[4];
            #pragma unroll
            for (int u2 = 0; u2 < 8; ++u2) {
                float4 x0 = LDS_F4(VOFF + 130,   u2);
                float4 x1 = LDS_F4(VOFF + t,     u2);
                float4 x2 = LDS_F4(VOFF + t + 1, u2);
                float4 x3 = LDS_F4(VOFF + t + 2, u2);
                float4 x4 = LDS_F4(VOFF + 131,   u2);
                float a0[4] = {x0.x, x0.y, x0.z, x0.w};
                float a1[4] = {x1.x, x1.y, x1.z, x1.w};
                float a2[4] = {x2.x, x2.y, x2.z, x2.w};
                float a3[4] = {x3.x, x3.y, x3.z, x3.w};
                float a4[4] = {x4.x, x4.y, x4.z, x4.w};
                #pragma unroll
                for (int e2 = 0; e2 < 4; ++e2) {
                    const int d = u2 * 4 + e2;
                    const float num = e[0] * a0[e2] + e[1] * a1[e2] + e[2] * a2[e2]
                                    + e[3] * a3[e2] + e[4] * a4[e2];
                    const float vp = a0[e2] + f1 * a1[e2] + a2[e2] + f3 * a3[e2] + a4[e2];
                    const float zd = (num + e0 * (vs_sh[d] - vp)) * rZ;
                    const unsigned short hb = f2bf(zd);
                    zh8[d >> 3][d & 7] = (short)hb;
                    zl8[d >> 3][d & 7] = (short)f2bf(zd - bf2f(hb));
                }
            }
            const int b = bh >> 3, h = bh & 7;
            const size_t o = (size_t)(b * L_ + i) * HD_ + h * DK_;
            #pragma unroll
            for (int u4 = 0; u4 < 4; ++u4) {
                *reinterpret_cast<bf16x8*>(&zh[o + u4 * 8]) = zh8[u4];
                *reinterpret_cast<bf16x8*>(&zl[o + u4 * 8]) = zl8[u4];
            }
        }
    } else {
        // ----------------- global rows: whole-row dense softmax -----------------
        const int bh = blk >> 1;
        const int r = (blk & 1) ? (L_ - 1) : 0;
        const float* qb = q + (size_t)bh * L_ * DK_;
        const float* kb = k + (size_t)bh * L_ * DK_;
        const float* vb = v + (size_t)bh * L_ * DK_;

        float* qs  = Sf;              // 32
        float* sc  = Sf + 32;         // 2048
        float* red = Sf + 2080;       // 8
        float* pzs = Sf + 2096;       // 128

        if (t < 32) qs[t] = qb[(size_t)r * DK_ + t];
        __syncthreads();

        float lmax = -1e30f;
        #pragma unroll
        for (int rep = 0; rep < 16; ++rep) {
            const int j = t + rep * 128;
            const float4* kr = reinterpret_cast<const float4*>(&kb[(size_t)j * DK_]);
            float p = 0.f;
            #pragma unroll
            for (int u = 0; u < 8; ++u) {
                float4 kv = kr[u];
                p += qs[u * 4 + 0] * kv.x + qs[u * 4 + 1] * kv.y
                   + qs[u * 4 + 2] * kv.z + qs[u * 4 + 3] * kv.w;
            }
            p *= RSQRT_DK;
            sc[j] = p;
            lmax = fmaxf(lmax, p);
        }
        #pragma unroll
        for (int off = 32; off; off >>= 1) lmax = fmaxf(lmax, __shfl_xor(lmax, off, 64));
        if ((t & 63) == 0) red[t >> 6] = lmax;
        __syncthreads();
        const float m = fmaxf(red[0], red[1]);

        float lsum = 0.f;
        #pragma unroll
        for (int rep = 0; rep < 16; ++rep) {
            const int j = t + rep * 128;
            const float e = __expf(sc[j] - m);
            sc[j] = e;
            lsum += e;
        }
        #pragma unroll
        for (int off = 32; off; off >>= 1) lsum += __shfl_xor(lsum, off, 64);
        if ((t & 63) == 0) red[2 + (t >> 6)] = lsum;
        __syncthreads();
        const float Z = red[2] + red[3];

        const int d = t & 31, g = t >> 5;
        float acc = 0.f;
        #pragma unroll 4
        for (int j = g * 512; j < g * 512 + 512; ++j)
            acc += sc[j] * vb[(size_t)j * DK_ + d];
        pzs[g * 32 + d] = acc;
        __syncthreads();
        if (g == 0) {
            const float zd = (pzs[d] + pzs[32 + d] + pzs[64 + d] + pzs[96 + d]) / Z;
            const int b = bh >> 3, h = bh & 7;
            const size_t o = (size_t)(b * L_ + r) * HD_ + h * DK_ + d;
            const unsigned short hb = f2bf(zd);
            zh[o] = hb;
            zl[o] = f2bf(zd - bf2f(hb));
        }
    }
    #undef LDS_F4
}

// ---------------------------------------------------------------------------
// K3: out = z @ WO + bO via split-bf16 MFMA, WO transpose fused (LDS,
// conflict-free layout).  Grid (64, 4), 256 thr = 4 waves; block tile 64x64,
// wave tile 16x64.
// ---------------------------------------------------------------------------
__global__ __launch_bounds__(256) void gemm_out_fused(
    const unsigned short* __restrict__ zh, const unsigned short* __restrict__ zl,
    const float* __restrict__ WO, const float* __restrict__ bO,
    float* __restrict__ out)
{
    const int bx = blockIdx.x;          // 0..63
    const int nt = blockIdx.y;          // 0..3
    const int n0 = nt * 64;

    __shared__ short WTh[64 * 256];
    __shared__ short WTl[64 * 256];

    const int tid = threadIdx.x;
    stage_wT(WO, n0, tid, WTh, WTl);
    __syncthreads();

    const int w  = tid >> 6;
    const int l  = tid & 63;
    const int lm = l & 15, lk8 = (l >> 4) * 8, cr = (l >> 4) * 4;
    const int R  = bx * 64 + w * 16;

    f32x4 acc[4];
    #pragma unroll
    for (int nf = 0; nf < 4; ++nf) acc[nf] = (f32x4){0.f, 0.f, 0.f, 0.f};

    bf16x8 Ah[2], Al[2];
    #define LOAD_Z(buf, ks)                                                          \
    {                                                                                \
        const size_t o = (size_t)(R + lm) * HD_ + (ks) * 32 + lk8;                   \
        Ah[buf] = *reinterpret_cast<const bf16x8*>(&zh[o]);                          \
        Al[buf] = *reinterpret_cast<const bf16x8*>(&zl[o]);                          \
    }
    LOAD_Z(0, 0)
    LOAD_Z(1, 1)

    #pragma unroll
    for (int ks = 0; ks < 8; ++ks) {
        const int cur = ks & 1;
        const bf16x8 a_h = Ah[cur], a_l = Al[cur];
        if (ks < 6) LOAD_Z(cur, ks + 2)
        #pragma unroll
        for (int nf = 0; nf < 4; ++nf) {
            const int o = WT_IDX(nf * 16 + lm, ks * 32 + lk8);
            const bf16x8 b_h = *reinterpret_cast<const bf16x8*>(&WTh[o]);
            const bf16x8 b_l = *reinterpret_cast<const bf16x8*>(&WTl[o]);
            acc[nf] = __builtin_amdgcn_mfma_f32_16x16x32_bf16(a_h, b_h, acc[nf], 0, 0, 0);
            acc[nf] = __builtin_amdgcn_mfma_f32_16x16x32_bf16(a_h, b_l, acc[nf], 0, 0, 0);
            acc[nf] = __builtin_amdgcn_mfma_f32_16x16x32_bf16(a_l, b_h, acc[nf], 0, 0, 0);
        }
    }
    #undef LOAD_Z

    #pragma unroll
    for (int nf = 0; nf < 4; ++nf) {
        const int col = n0 + nf * 16 + lm;
        const float bb = bO[col];
        #pragma unroll
        for (int r = 0; r < 4; ++r) {
            const int m = R + cr + r;
            out[(size_t)m * HD_ + col] = acc[nf][r] + bb;
        }
    }
}

// ---------------------------------------------------------------------------
extern "C" void kernel_launch(void* const* d_in, const int* in_sizes, int n_in,
                              void* d_out, int out_size, void* d_ws, size_t ws_size,
                              hipStream_t stream)
{
    const float* qx = (const float*)d_in[0];
    const float* kx = (const float*)d_in[1];
    const float* vx = (const float*)d_in[2];
    const float* WQ = (const float*)d_in[3];
    const float* bQ = (const float*)d_in[4];
    const float* WK = (const float*)d_in[5];
    const float* bK = (const float*)d_in[6];
    const float* WV = (const float*)d_in[7];
    const float* bV = (const float*)d_in[8];
    const float* WO = (const float*)d_in[9];
    const float* bO = (const float*)d_in[10];
    float* out = (float*)d_out;

    char* wsb = (char*)d_ws;
    float*          q    = (float*)(wsb);
    float*          k    = (float*)(wsb + (4u  << 20));
    float*          v    = (float*)(wsb + (8u  << 20));
    unsigned short* zh   = (unsigned short*)(wsb + (12u << 20));
    unsigned short* zl   = (unsigned short*)(wsb + (14u << 20));
    float*          part = (float*)(wsb + (16u << 20));   // 16 bh x 32 d x 16 = 32 KB

    gemm_qkv_fused<<<dim3(32, 12), 256, 0, stream>>>(qx, kx, vx, WQ, bQ, WK, bK, WV, bV, q, k, v, part);
    attn_main<<<288, 128, 0, stream>>>(q, k, v, part, zh, zl);
    gemm_out_fused<<<dim3(64, 4), 256, 0, stream>>>(zh, zl, WO, bO, out);
}

// Round 7
// 44.258 us; speedup vs baseline: 1.6456x; 1.6456x over previous
//
#include <hip/hip_runtime.h>
#include <hip/hip_bf16.h>

#define B_   2
#define L_   2048
#define C_   256
#define H_   8
#define DK_  32
#define HD_  256
#define RSQRT_DK 0.17677669529663687f  // 1/sqrt(32)

typedef __attribute__((ext_vector_type(8))) short bf16x8;
typedef __attribute__((ext_vector_type(4))) float f32x4;

__device__ __forceinline__ unsigned short f2bf(float x) {
    unsigned int u = __float_as_uint(x);
    u += 0x7fffu + ((u >> 16) & 1u);
    return (unsigned short)(u >> 16);
}
__device__ __forceinline__ float bf2f(unsigned short h) {
    return __uint_as_float((unsigned int)h << 16);
}

// ---------------------------------------------------------------------------
// Split-bf16 transposed weight slice in LDS: plane[64][256] shorts.
// Row pitch = 128 dwords (== 0 mod 32 banks -> uniform row bank base).
// 16B chunk index swizzled: chunk' = chunk ^ (n & 7)  (st_16x32-style).
// Both ds_write_b128 staging and ds_read_b128 frag reads sit at the b128
// bank floor (uniform 8-deep).
// ---------------------------------------------------------------------------
#define WT_IDX(n, k) (((n) << 8) + (((((k) >> 3) ^ ((n) & 7))) << 3) + ((k) & 7))

// Stage W cols [n0, n0+63], k 0..255 into LDS planes as split-bf16 [n][k].
// 256 threads: wave w handles k-rows [w*64, w*64+63]; lane n = tid&63.
// Global loads: 64 consecutive lanes read 64 consecutive floats (coalesced).
__device__ __forceinline__ void stage_wT(
    const float* __restrict__ W, int n0, int tid,
    short* __restrict__ WTh, short* __restrict__ WTl)
{
    const int n  = tid & 63;
    const int kc = tid >> 6;           // 0..3
    #pragma unroll
    for (int c8 = 0; c8 < 8; ++c8) {
        const int k0 = kc * 64 + c8 * 8;
        bf16x8 hv, lv;
        #pragma unroll
        for (int e = 0; e < 8; ++e) {
            const float x = W[(size_t)(k0 + e) * HD_ + n0 + n];
            const unsigned short h = f2bf(x);
            hv[e] = (short)h;
            lv[e] = (short)f2bf(x - bf2f(h));
        }
        const int o = (n << 8) + ((((k0 >> 3) ^ (n & 7))) << 3);
        *reinterpret_cast<bf16x8*>(&WTh[o]) = hv;
        *reinterpret_cast<bf16x8*>(&WTl[o]) = lv;
    }
}

// ---------------------------------------------------------------------------
// K1: QKV projection, split-bf16 MFMA, fused weight transpose (LDS,
// conflict-free), deterministic per-block V column-sum partials.
// Grid (32, 12 = proj*4 + nt), 256 thr = 4 waves; block tile 128x64,
// wave tile 32x64.  (unchanged from round 6)
// ---------------------------------------------------------------------------
__global__ __launch_bounds__(256) void gemm_qkv_fused(
    const float* __restrict__ qx, const float* __restrict__ kx, const float* __restrict__ vx,
    const float* __restrict__ WQ, const float* __restrict__ bQ,
    const float* __restrict__ WK, const float* __restrict__ bK,
    const float* __restrict__ WV, const float* __restrict__ bV,
    float* __restrict__ q, float* __restrict__ k, float* __restrict__ v,
    float* __restrict__ part)
{
    const int bx = blockIdx.x;          // 0..31
    const int yy = blockIdx.y;          // 0..11
    const int proj = yy >> 2, nt = yy & 3;
    const float* A    = proj == 0 ? qx : (proj == 1 ? kx : vx);
    const float* W    = proj == 0 ? WQ : (proj == 1 ? WK : WV);
    const float* bias = proj == 0 ? bQ : (proj == 1 ? bK : bV);
    float* out        = proj == 0 ? q  : (proj == 1 ? k  : v);
    const int n0 = nt * 64;

    __shared__ short WTh[64 * 256];
    __shared__ short WTl[64 * 256];
    __shared__ float red[4][4][16];

    const int tid = threadIdx.x;
    stage_wT(W, n0, tid, WTh, WTl);
    __syncthreads();

    const int w  = tid >> 6;            // wave 0..3
    const int l  = tid & 63;
    const int lm = l & 15, lk8 = (l >> 4) * 8, cr = (l >> 4) * 4;
    const int R  = bx * 128 + w * 32;

    f32x4 acc[2][4];
    #pragma unroll
    for (int mf = 0; mf < 2; ++mf)
        #pragma unroll
        for (int nf = 0; nf < 4; ++nf)
            acc[mf][nf] = (f32x4){0.f, 0.f, 0.f, 0.f};

    float4 Ab[2][4];
    #define LOAD_A(buf, ks)                                                          \
    {                                                                                \
        const float* p0 = &A[(size_t)(R + lm) * C_ + (ks) * 32 + lk8];               \
        const float* p1 = &A[(size_t)(R + 16 + lm) * C_ + (ks) * 32 + lk8];          \
        Ab[buf][0] = *reinterpret_cast<const float4*>(p0);                           \
        Ab[buf][1] = *reinterpret_cast<const float4*>(p0 + 4);                       \
        Ab[buf][2] = *reinterpret_cast<const float4*>(p1);                           \
        Ab[buf][3] = *reinterpret_cast<const float4*>(p1 + 4);                       \
    }
    LOAD_A(0, 0)
    LOAD_A(1, 1)

    #pragma unroll
    for (int ks = 0; ks < 8; ++ks) {
        const int cur = ks & 1;
        bf16x8 ah[2], al[2];
        #pragma unroll
        for (int mf = 0; mf < 2; ++mf) {
            float4 v0 = Ab[cur][mf * 2], v1 = Ab[cur][mf * 2 + 1];
            float xs[8] = {v0.x, v0.y, v0.z, v0.w, v1.x, v1.y, v1.z, v1.w};
            #pragma unroll
            for (int e = 0; e < 8; ++e) {
                const unsigned short h = f2bf(xs[e]);
                ah[mf][e] = (short)h;
                al[mf][e] = (short)f2bf(xs[e] - bf2f(h));
            }
        }
        if (ks < 6) LOAD_A(cur, ks + 2)
        bf16x8 Bh[4], Bl[4];
        #pragma unroll
        for (int nf = 0; nf < 4; ++nf) {
            const int o = WT_IDX(nf * 16 + lm, ks * 32 + lk8);
            Bh[nf] = *reinterpret_cast<const bf16x8*>(&WTh[o]);
            Bl[nf] = *reinterpret_cast<const bf16x8*>(&WTl[o]);
        }
        #pragma unroll
        for (int mf = 0; mf < 2; ++mf)
            #pragma unroll
            for (int nf = 0; nf < 4; ++nf) {
                acc[mf][nf] = __builtin_amdgcn_mfma_f32_16x16x32_bf16(ah[mf], Bh[nf], acc[mf][nf], 0, 0, 0);
                acc[mf][nf] = __builtin_amdgcn_mfma_f32_16x16x32_bf16(ah[mf], Bl[nf], acc[mf][nf], 0, 0, 0);
                acc[mf][nf] = __builtin_amdgcn_mfma_f32_16x16x32_bf16(al[mf], Bh[nf], acc[mf][nf], 0, 0, 0);
            }
    }
    #undef LOAD_A

    // epilogue: bias + scatter to (B,H,L,DK)
    #pragma unroll
    for (int mf = 0; mf < 2; ++mf)
        #pragma unroll
        for (int nf = 0; nf < 4; ++nf) {
            const int col = n0 + nf * 16 + lm;
            const int h = col >> 5, d = col & 31;
            const float bb = bias[col];
            #pragma unroll
            for (int r = 0; r < 4; ++r) {
                const int m = R + mf * 16 + cr + r;
                const int b = m >> 11, lrow = m & (L_ - 1);
                out[((size_t)(b * H_ + h) * L_ + lrow) * DK_ + d] = acc[mf][nf][r] + bb;
            }
        }

    // V column-sum partials (deterministic, per block = 128 rows x 64 cols)
    if (proj == 2) {
        float sl[4];
        #pragma unroll
        for (int nf = 0; nf < 4; ++nf) {
            float s = 0.f;
            #pragma unroll
            for (int mf = 0; mf < 2; ++mf)
                #pragma unroll
                for (int r = 0; r < 4; ++r) s += acc[mf][nf][r];
            s += __shfl_xor(s, 16);
            s += __shfl_xor(s, 32);
            sl[nf] = s;
        }
        if (l < 16) {
            #pragma unroll
            for (int nf = 0; nf < 4; ++nf) red[w][nf][l] = sl[nf];
        }
        __syncthreads();
        if (tid < 64) {
            const int nf = tid >> 4, lmm = tid & 15;
            float tot = red[0][nf][lmm] + red[1][nf][lmm] + red[2][nf][lmm] + red[3][nf][lmm];
            const int col = n0 + nf * 16 + lmm;
            tot += 128.f * bias[col];
            const int h = col >> 5, d = col & 31;
            const int bh = (bx >> 4) * H_ + h;       // block spans one b
            part[((size_t)bh * 32 + d) * 16 + (bx & 15)] = tot;
        }
    }
}

// ---------------------------------------------------------------------------
// K2: attention (round-5 structure).
//  Blocks 0..255   : interior rows, ONE ROW PER LANE (bh = blk>>4, 128-row
//                    chunk = blk&15), K/V/Q staged in LDS, XOR-quad swizzle.
//  Blocks 256..767 : global-row partials (bh, row-pair, 128-col chunk).
// 128 threads (2 waves) per block.
// ---------------------------------------------------------------------------
#define NSLOT 392            // 132 K + 132 V + 128 Q
#define KOFF  0
#define VOFF  132
#define QOFF  264

__global__ __launch_bounds__(128) void attn_main(
    const float* __restrict__ q, const float* __restrict__ k,
    const float* __restrict__ v, const float* __restrict__ part,
    float* __restrict__ pm, float* __restrict__ pZ, float* __restrict__ pzv,
    unsigned short* __restrict__ zh, unsigned short* __restrict__ zl)
{
    __shared__ float Sf[NSLOT * 32 + 32];
    float* vs_sh = &Sf[NSLOT * 32];

    // logical (slot, quad, elem) -> phys dword: slot*32 + ((quad ^ (slot&7))<<2) + elem
    #define LDS_F4(slot, u2) (*reinterpret_cast<const float4*>(&Sf[((slot) << 5) + (((u2) ^ ((slot) & 7)) << 2)]))

    const int blk = blockIdx.x;
    const int t = threadIdx.x;

    if (blk < 256) {
        // ----------------- interior rows, per-lane -----------------
        const int bh = blk >> 4, c = blk & 15;
        const int base = c * 128;                   // slot s (<130) = row base+s
        const float* qb = q + (size_t)bh * L_ * DK_;
        const float* kb = k + (size_t)bh * L_ * DK_;
        const float* vb = v + (size_t)bh * L_ * DK_;

        // stage K(132 slots) V(132) Q(128) = 3136 float4 units
        for (int u = t; u < NSLOT * 8; u += 128) {
            const int slot = u >> 3, quad = u & 7;
            int row; const float* src;
            if (slot < VOFF) {
                const int s = slot;
                row = (s < 130) ? min(base + s, L_ - 1) : ((s == 130) ? 0 : L_ - 1);
                src = kb;
            } else if (slot < QOFF) {
                const int s = slot - VOFF;
                row = (s < 130) ? min(base + s, L_ - 1) : ((s == 130) ? 0 : L_ - 1);
                src = vb;
            } else {
                row = min(base + 1 + (slot - QOFF), L_ - 1);
                src = qb;
            }
            float4 w4 = *reinterpret_cast<const float4*>(&src[(size_t)row * DK_ + quad * 4]);
            float* dst = &Sf[(slot << 5) + ((quad ^ (slot & 7)) << 2)];
            dst[0] = w4.x; dst[1] = w4.y; dst[2] = w4.z; dst[3] = w4.w;
        }
        if (t < 32) {
            const float4* pp = reinterpret_cast<const float4*>(&part[((size_t)bh * 32 + t) * 16]);
            float4 pa = pp[0], pb = pp[1], pc = pp[2], pd = pp[3];
            vs_sh[t] = pa.x + pa.y + pa.z + pa.w + pb.x + pb.y + pb.z + pb.w
                     + pc.x + pc.y + pc.z + pc.w + pd.x + pd.y + pd.z + pd.w;
        }
        __syncthreads();

        const int i = base + 1 + t;
        if (i <= L_ - 2) {
            float qr[32];
            {
                const int qs = QOFF + t;
                #pragma unroll
                for (int u2 = 0; u2 < 8; ++u2) {
                    float4 x = LDS_F4(qs, u2);
                    qr[u2 * 4 + 0] = x.x; qr[u2 * 4 + 1] = x.y;
                    qr[u2 * 4 + 2] = x.z; qr[u2 * 4 + 3] = x.w;
                }
            }
            const int ks_[5] = {130, t, t + 1, t + 2, 131};   // cols 0, i-1, i, i+1, L-1
            float sv[5];
            #pragma unroll
            for (int jj = 0; jj < 5; ++jj) {
                const int s = ks_[jj];
                float p = 0.f;
                #pragma unroll
                for (int u2 = 0; u2 < 8; ++u2) {
                    float4 kv = LDS_F4(s, u2);
                    p += qr[u2 * 4 + 0] * kv.x + qr[u2 * 4 + 1] * kv.y
                       + qr[u2 * 4 + 2] * kv.z + qr[u2 * 4 + 3] * kv.w;
                }
                sv[jj] = p * RSQRT_DK;
            }
            const bool v1 = (i != 1), v3 = (i != L_ - 2);
            float m = fmaxf(0.f, sv[0]);                 // zero fillers join the max
            m = fmaxf(m, sv[2]); m = fmaxf(m, sv[4]);
            if (v1) m = fmaxf(m, sv[1]);
            if (v3) m = fmaxf(m, sv[3]);
            float e[5];
            e[0] = __expf(sv[0] - m);
            e[1] = v1 ? __expf(sv[1] - m) : 0.f;
            e[2] = __expf(sv[2] - m);
            e[3] = v3 ? __expf(sv[3] - m) : 0.f;
            e[4] = __expf(sv[4] - m);
            const int ns = 3 + (int)v1 + (int)v3;
            const float e0 = __expf(-m);
            const float Z = e[0] + e[1] + e[2] + e[3] + e[4] + (float)(L_ - ns) * e0;
            const float rZ = 1.f / Z;
            const float f1 = v1 ? 1.f : 0.f, f3 = v3 ? 1.f : 0.f;

            bf16x8 zh8[4], zl8[4];
            #pragma unroll
            for (int u2 = 0; u2 < 8; ++u2) {
                float4 x0 = LDS_F4(VOFF + 130,   u2);
                float4 x1 = LDS_F4(VOFF + t,     u2);
                float4 x2 = LDS_F4(VOFF + t + 1, u2);
                float4 x3 = LDS_F4(VOFF + t + 2, u2);
                float4 x4 = LDS_F4(VOFF + 131,   u2);
                float a0[4] = {x0.x, x0.y, x0.z, x0.w};
                float a1[4] = {x1.x, x1.y, x1.z, x1.w};
                float a2[4] = {x2.x, x2.y, x2.z, x2.w};
                float a3[4] = {x3.x, x3.y, x3.z, x3.w};
                float a4[4] = {x4.x, x4.y, x4.z, x4.w};
                #pragma unroll
                for (int e2 = 0; e2 < 4; ++e2) {
                    const int d = u2 * 4 + e2;
                    const float num = e[0] * a0[e2] + e[1] * a1[e2] + e[2] * a2[e2]
                                    + e[3] * a3[e2] + e[4] * a4[e2];
                    const float vp = a0[e2] + f1 * a1[e2] + a2[e2] + f3 * a3[e2] + a4[e2];
                    const float zd = (num + e0 * (vs_sh[d] - vp)) * rZ;
                    const unsigned short hb = f2bf(zd);
                    zh8[d >> 3][d & 7] = (short)hb;
                    zl8[d >> 3][d & 7] = (short)f2bf(zd - bf2f(hb));
                }
            }
            const int b = bh >> 3, h = bh & 7;
            const size_t o = (size_t)(b * L_ + i) * HD_ + h * DK_;
            #pragma unroll
            for (int u4 = 0; u4 < 4; ++u4) {
                *reinterpret_cast<bf16x8*>(&zh[o + u4 * 8]) = zh8[u4];
                *reinterpret_cast<bf16x8*>(&zl[o + u4 * 8]) = zl8[u4];
            }
        }
    } else {
        // ----------------- global-row partials -----------------
        const int blk2 = blk - 256;                 // 0..511
        const int bh = blk2 >> 5;
        const int pair = (blk2 >> 4) & 1;
        const int chunk = blk2 & 15;
        const int r = pair ? (L_ - 1) : 0;
        const int j0 = chunk * 128;
        const float* qb = q + (size_t)bh * L_ * DK_;
        const float* kb = k + (size_t)bh * L_ * DK_;
        const float* vb = v + (size_t)bh * L_ * DK_;

        float* qs  = Sf;          // 32
        float* sc  = Sf + 32;     // 128
        float* red = Sf + 160;    // 4
        float* pzs = Sf + 192;    // 128

        if (t < 32) qs[t] = qb[(size_t)r * DK_ + t];
        __syncthreads();

        const int j = j0 + t;
        const float4* kr = reinterpret_cast<const float4*>(&kb[(size_t)j * DK_]);
        float p = 0.f;
        #pragma unroll
        for (int u = 0; u < 8; ++u) {
            float4 kv = kr[u];
            p += qs[u * 4 + 0] * kv.x + qs[u * 4 + 1] * kv.y
               + qs[u * 4 + 2] * kv.z + qs[u * 4 + 3] * kv.w;
        }
        p *= RSQRT_DK;

        float lm = p;
        #pragma unroll
        for (int off = 32; off; off >>= 1) lm = fmaxf(lm, __shfl_xor(lm, off, 64));
        if ((t & 63) == 0) red[t >> 6] = lm;
        __syncthreads();
        const float m = fmaxf(red[0], red[1]);

        const float e = __expf(p - m);
        sc[t] = e;
        float ls = e;
        #pragma unroll
        for (int off = 32; off; off >>= 1) ls += __shfl_xor(ls, off, 64);
        if ((t & 63) == 0) red[2 + (t >> 6)] = ls;
        __syncthreads();
        const float Zc = red[2] + red[3];

        const int d = t & 31, g = t >> 5;
        float acc = 0.f;
        #pragma unroll 4
        for (int jj = 0; jj < 32; ++jj)
            acc += sc[g * 32 + jj] * vb[(size_t)(j0 + g * 32 + jj) * DK_ + d];
        pzs[g * 32 + d] = acc;
        __syncthreads();
        if (g == 0) {
            const float s2 = pzs[d] + pzs[32 + d] + pzs[64 + d] + pzs[96 + d];
            pzv[(size_t)blk2 * 32 + d] = s2;
        }
        if (t == 0) { pm[blk2] = m; pZ[blk2] = Zc; }
    }
    #undef LDS_F4
}

// ---------------------------------------------------------------------------
// K2b: combine 16 chunks per global row; write z hi/lo.  1 block.
// ---------------------------------------------------------------------------
__global__ __launch_bounds__(1024) void attn_g2_kernel(
    const float* __restrict__ pm, const float* __restrict__ pZ,
    const float* __restrict__ pzv,
    unsigned short* __restrict__ zh, unsigned short* __restrict__ zl)
{
    const int t = threadIdx.x;           // 0..1023
    const int rowIdx = t >> 5;           // 0..31 (= bh*2 + pair)
    const int d = t & 31;
    const int bh = rowIdx >> 1, pair = rowIdx & 1;
    const int base = rowIdx * 16;

    float m = -1e30f;
    #pragma unroll
    for (int c = 0; c < 16; ++c) m = fmaxf(m, pm[base + c]);
    float Z = 0.f, zd = 0.f;
    #pragma unroll
    for (int c = 0; c < 16; ++c) {
        const float w = __expf(pm[base + c] - m);
        Z  += pZ[base + c] * w;
        zd += pzv[(size_t)(base + c) * 32 + d] * w;
    }
    zd /= Z;

    const int r = pair ? (L_ - 1) : 0;
    const int b = bh >> 3, h = bh & 7;
    const size_t o = (size_t)(b * L_ + r) * HD_ + h * DK_ + d;
    const unsigned short hb = f2bf(zd);
    zh[o] = hb;
    zl[o] = f2bf(zd - bf2f(hb));
}

// ---------------------------------------------------------------------------
// K3: out = z @ WO + bO via split-bf16 MFMA, WO transpose fused (LDS,
// conflict-free layout).  Grid (64, 4), 256 thr = 4 waves; block tile 64x64,
// wave tile 16x64.  (unchanged from round 6)
// ---------------------------------------------------------------------------
__global__ __launch_bounds__(256) void gemm_out_fused(
    const unsigned short* __restrict__ zh, const unsigned short* __restrict__ zl,
    const float* __restrict__ WO, const float* __restrict__ bO,
    float* __restrict__ out)
{
    const int bx = blockIdx.x;          // 0..63
    const int nt = blockIdx.y;          // 0..3
    const int n0 = nt * 64;

    __shared__ short WTh[64 * 256];
    __shared__ short WTl[64 * 256];

    const int tid = threadIdx.x;
    stage_wT(WO, n0, tid, WTh, WTl);
    __syncthreads();

    const int w  = tid >> 6;
    const int l  = tid & 63;
    const int lm = l & 15, lk8 = (l >> 4) * 8, cr = (l >> 4) * 4;
    const int R  = bx * 64 + w * 16;

    f32x4 acc[4];
    #pragma unroll
    for (int nf = 0; nf < 4; ++nf) acc[nf] = (f32x4){0.f, 0.f, 0.f, 0.f};

    bf16x8 Ah[2], Al[2];
    #define LOAD_Z(buf, ks)                                                          \
    {                                                                                \
        const size_t o = (size_t)(R + lm) * HD_ + (ks) * 32 + lk8;                   \
        Ah[buf] = *reinterpret_cast<const bf16x8*>(&zh[o]);                          \
        Al[buf] = *reinterpret_cast<const bf16x8*>(&zl[o]);                          \
    }
    LOAD_Z(0, 0)
    LOAD_Z(1, 1)

    #pragma unroll
    for (int ks = 0; ks < 8; ++ks) {
        const int cur = ks & 1;
        const bf16x8 a_h = Ah[cur], a_l = Al[cur];
        if (ks < 6) LOAD_Z(cur, ks + 2)
        #pragma unroll
        for (int nf = 0; nf < 4; ++nf) {
            const int o = WT_IDX(nf * 16 + lm, ks * 32 + lk8);
            const bf16x8 b_h = *reinterpret_cast<const bf16x8*>(&WTh[o]);
            const bf16x8 b_l = *reinterpret_cast<const bf16x8*>(&WTl[o]);
            acc[nf] = __builtin_amdgcn_mfma_f32_16x16x32_bf16(a_h, b_h, acc[nf], 0, 0, 0);
            acc[nf] = __builtin_amdgcn_mfma_f32_16x16x32_bf16(a_h, b_l, acc[nf], 0, 0, 0);
            acc[nf] = __builtin_amdgcn_mfma_f32_16x16x32_bf16(a_l, b_h, acc[nf], 0, 0, 0);
        }
    }
    #undef LOAD_Z

    #pragma unroll
    for (int nf = 0; nf < 4; ++nf) {
        const int col = n0 + nf * 16 + lm;
        const float bb = bO[col];
        #pragma unroll
        for (int r = 0; r < 4; ++r) {
            const int m = R + cr + r;
            out[(size_t)m * HD_ + col] = acc[nf][r] + bb;
        }
    }
}

// ---------------------------------------------------------------------------
extern "C" void kernel_launch(void* const* d_in, const int* in_sizes, int n_in,
                              void* d_out, int out_size, void* d_ws, size_t ws_size,
                              hipStream_t stream)
{
    const float* qx = (const float*)d_in[0];
    const float* kx = (const float*)d_in[1];
    const float* vx = (const float*)d_in[2];
    const float* WQ = (const float*)d_in[3];
    const float* bQ = (const float*)d_in[4];
    const float* WK = (const float*)d_in[5];
    const float* bK = (const float*)d_in[6];
    const float* WV = (const float*)d_in[7];
    const float* bV = (const float*)d_in[8];
    const float* WO = (const float*)d_in[9];
    const float* bO = (const float*)d_in[10];
    float* out = (float*)d_out;

    char* wsb = (char*)d_ws;
    float*          q    = (float*)(wsb);
    float*          k    = (float*)(wsb + (4u  << 20));
    float*          v    = (float*)(wsb + (8u  << 20));
    unsigned short* zh   = (unsigned short*)(wsb + (12u << 20));
    unsigned short* zl   = (unsigned short*)(wsb + (14u << 20));
    float*          part = (float*)(wsb + (16u << 20));              // 32 KB
    float*          pm   = (float*)(wsb + (16u << 20) + (1u << 16)); // 512 f
    float*          pZ   = pm + 512;
    float*          pzv  = pm + 1024;                                // 16384 f

    gemm_qkv_fused<<<dim3(32, 12), 256, 0, stream>>>(qx, kx, vx, WQ, bQ, WK, bK, WV, bV, q, k, v, part);
    attn_main<<<768, 128, 0, stream>>>(q, k, v, part, pm, pZ, pzv, zh, zl);
    attn_g2_kernel<<<1, 1024, 0, stream>>>(pm, pZ, pzv, zh, zl);
    gemm_out_fused<<<dim3(64, 4), 256, 0, stream>>>(zh, zl, WO, bO, out);
}